// Round 3
// baseline (267.817 us; speedup 1.0000x reference)
//
#include <hip/hip_runtime.h>
#include <hip/hip_bf16.h>

// Problem constants
#define XH   64
#define XW   64
#define CIN  256
#define COUT 256
#define BATCH 4
#define KK9  9
#define M_TOT 16384      // BATCH*XH*XW
#define K_TOT 2304       // KK9*CIN
#define NKSTEP 36        // K_TOT/64
#define NCHUNK 32        // k1 channel split (8 ch each)

typedef __attribute__((ext_vector_type(8))) short short8;
typedef __attribute__((ext_vector_type(4))) short short4v;
typedef __attribute__((ext_vector_type(4))) float f32x4;
typedef __attribute__((ext_vector_type(4))) int int4v;

// Workspace layout (bytes).
// PART aliases VT: k1a/k1b finish before k2 writes Vt.
#define OM_OFF   0
#define OM_BYTES (BATCH*27*4096*4)            // 1,769,472
#define XT_OFF   (OM_OFF + OM_BYTES)
#define XT_BYTES (BATCH*4096*CIN*4)           // 16,777,216
#define WT_OFF   (XT_OFF + XT_BYTES)
#define WT_BYTES (COUT*K_TOT*2)               // 1,179,648
#define VT_OFF   (WT_OFF + WT_BYTES)
#define VT_BYTES (M_TOT*K_TOT*2)              // 75,497,472
#define PART_OFF VT_OFF                       // 56,623,104 < VT_BYTES, dead before k2

__device__ __forceinline__ void async16(const void* g, void* l) {
  __builtin_amdgcn_global_load_lds((const __attribute__((address_space(1))) void*)g,
                                   (__attribute__((address_space(3))) void*)l,
                                   16, 0, 0);
}

// ---------------------------------------------------------------------------
// K0: w_conv (O,C,3,3) f32  ->  Wt tiled bf16: [to(2)][tk(36)][128 o][64 k],
//     k = kk*256 + c
// ---------------------------------------------------------------------------
__global__ __launch_bounds__(256) void k0_wt(const float* __restrict__ wconv,
                                             __hip_bfloat16* __restrict__ Wt) {
  int e = blockIdx.x * 256 + threadIdx.x;      // < 256*2304 = 589824
  int t  = e >> 13;                            // tile index to*36+tk
  int r  = e & 8191;
  int ol = r >> 6, kl = r & 63;
  int to = t / 36, tk = t - to * 36;
  int o  = to * 128 + ol;
  int k  = tk * 64 + kl;
  int kk = k >> 8, c = k & 255;
  float v = wconv[(o * CIN + c) * KK9 + kk];
  Wt[e] = __float2bfloat16(v);
}

// ---------------------------------------------------------------------------
// K1a: offset conv partials. grid (64 pos-blocks, 32 c-chunks), 256 thr.
// 8 channels per thread -> 2048 blocks (8/CU, full occupancy).
// part[chunk][oc][p] , p = b*4096 + h*64 + w
// ---------------------------------------------------------------------------
__global__ __launch_bounds__(256) void k1a_offconv(const float* __restrict__ x,
                                                   const float* __restrict__ woff,
                                                   float* __restrict__ part) {
  int p = blockIdx.x * 256 + threadIdx.x;
  int chunk = blockIdx.y;
  int b = p >> 12, hw = p & 4095, h = hw >> 6, w = hw & 63;
  int c0 = chunk * 8;
  const float* xb = x + (size_t)(b * CIN + c0) * 4096;
  float acc[27];
#pragma unroll
  for (int i = 0; i < 27; ++i) acc[i] = 0.f;

#pragma unroll
  for (int ci = 0; ci < 8; ++ci) {
    float xv[9];
#pragma unroll
    for (int ky = 0; ky < 3; ++ky) {
      int yy = h + ky - 1;
      bool rok = (unsigned)yy < 64u;
#pragma unroll
      for (int kx = 0; kx < 3; ++kx) {
        int xx = w + kx - 1;
        bool ok = rok && ((unsigned)xx < 64u);
        xv[ky * 3 + kx] = ok ? xb[ci * 4096 + yy * 64 + xx] : 0.f;
      }
    }
    const float* wp = woff + (size_t)(c0 + ci) * 9;
#pragma unroll
    for (int oc = 0; oc < 27; ++oc) {
#pragma unroll
      for (int j = 0; j < 9; ++j)
        acc[oc] = fmaf(xv[j], wp[oc * 2304 + j], acc[oc]);
    }
  }
#pragma unroll
  for (int oc = 0; oc < 27; ++oc)
    part[((size_t)(chunk * 27 + oc) << 14) + p] = acc[oc];
}

// ---------------------------------------------------------------------------
// K1b: reduce 32 partials + bias -> om[(b*27+oc)*4096 + hw]
// ---------------------------------------------------------------------------
__global__ __launch_bounds__(256) void k1b_reduce(const float* __restrict__ part,
                                                  const float* __restrict__ boff,
                                                  float* __restrict__ om) {
  int t = blockIdx.x * 256 + threadIdx.x;   // < 27*16384
  int oc = t >> 14, p = t & 16383;
  float s = boff[oc];
#pragma unroll
  for (int ch = 0; ch < NCHUNK; ++ch) s += part[((size_t)(ch * 27 + oc) << 14) + p];
  int b = p >> 12, hw = p & 4095;
  om[(size_t)(b * 27 + oc) * 4096 + hw] = s;
}

// ---------------------------------------------------------------------------
// KT: transpose x (B,C,H,W) f32 -> xT[b][hw][c] f32 (channel-contiguous)
// ---------------------------------------------------------------------------
__global__ __launch_bounds__(256) void kt_xt(const float* __restrict__ x,
                                             float* __restrict__ xT) {
  __shared__ float t[64][65];
  int blk = blockIdx.x;
  int hwg = blk & 63;
  int cg  = (blk >> 6) & 3;
  int b   = blk >> 8;
  int hw0 = hwg * 64, c0 = cg * 64;
  int l = threadIdx.x & 63, q = threadIdx.x >> 6;
  const float* xb = x + ((size_t)(b * 256 + c0) << 12) + hw0;
#pragma unroll
  for (int i = 0; i < 16; ++i) {
    int cl = q * 16 + i;
    t[cl][l] = xb[((size_t)cl << 12) + l];
  }
  __syncthreads();
  float* xTb = xT + (((size_t)b << 12) + hw0) * 256 + c0;
#pragma unroll
  for (int i = 0; i < 16; ++i) {
    int hwl = q * 16 + i;
    xTb[(size_t)hwl * 256 + l] = t[l][hwl];
  }
}

// ---------------------------------------------------------------------------
// K2: deformable im2col from xT -> Vt tiled bf16: [tm2(256)][tk(36)][64 m][64 k]
// One WAVE per (m); lane = 4 channels (float4); 9 kk per wave.
// ---------------------------------------------------------------------------
__global__ __launch_bounds__(256) void k2_im2col(const float* __restrict__ xT,
                                                 const float* __restrict__ om,
                                                 __hip_bfloat16* __restrict__ Vt) {
  int wv = threadIdx.x >> 6, lane = threadIdx.x & 63;
  int m = blockIdx.x * 4 + wv;
  int b = m >> 12, hw = m & 4095, h = hw >> 6, w = hw & 63;
  const float* omb = om + ((size_t)(b * 27) << 12) + hw;

  float dyv[9], dxv[9], mzv[9];
#pragma unroll
  for (int kk = 0; kk < 9; ++kk) {
    dyv[kk] = omb[(size_t)(2 * kk) << 12];
    dxv[kk] = omb[(size_t)(2 * kk + 1) << 12];
    mzv[kk] = omb[(size_t)(18 + kk) << 12];
  }

  const float* xb = xT + (((size_t)b << 12) << 8) + lane * 4;
  int tm2 = m >> 6, ml = m & 63;
  int cc = lane >> 4;
  int kl4 = (lane & 15) * 4;

#pragma unroll
  for (int kk = 0; kk < 9; ++kk) {
    int ky = kk / 3, kx = kk - ky * 3;
    float py = dyv[kk] + (float)(h - 1 + ky);
    float px = dxv[kk] + (float)(w - 1 + kx);
    float y0f = floorf(py), x0f = floorf(px);
    float wy = py - y0f, wx = px - x0f;
    int y0 = (int)y0f, x0 = (int)x0f;
    bool vy0 = (unsigned)y0 < 64u, vy1 = (unsigned)(y0 + 1) < 64u;
    bool vx0 = (unsigned)x0 < 64u, vx1 = (unsigned)(x0 + 1) < 64u;
    int cy0 = min(max(y0, 0), 63), cy1 = min(max(y0 + 1, 0), 63);
    int cx0 = min(max(x0, 0), 63), cx1 = min(max(x0 + 1, 0), 63);
    float mask = 1.f / (1.f + __expf(-mzv[kk]));
    float w00 = (vy0 && vx0) ? (1.f - wy) * (1.f - wx) * mask : 0.f;
    float w01 = (vy0 && vx1) ? (1.f - wy) * wx * mask : 0.f;
    float w10 = (vy1 && vx0) ? wy * (1.f - wx) * mask : 0.f;
    float w11 = (vy1 && vx1) ? wy * wx * mask : 0.f;

    f32x4 t00 = *(const f32x4*)(xb + (size_t)(cy0 * 64 + cx0) * 256);
    f32x4 t01 = *(const f32x4*)(xb + (size_t)(cy0 * 64 + cx1) * 256);
    f32x4 t10 = *(const f32x4*)(xb + (size_t)(cy1 * 64 + cx0) * 256);
    f32x4 t11 = *(const f32x4*)(xb + (size_t)(cy1 * 64 + cx1) * 256);

    f32x4 v;
#pragma unroll
    for (int j = 0; j < 4; ++j)
      v[j] = w00 * t00[j] + w01 * t01[j] + w10 * t10[j] + w11 * t11[j];

    __hip_bfloat16 h4[4];
#pragma unroll
    for (int j = 0; j < 4; ++j) h4[j] = __float2bfloat16(v[j]);

    int tk = kk * 4 + cc;
    size_t dst = (((size_t)(tm2 * 36 + tk)) << 12) + (size_t)ml * 64 + kl4;
    *(short4v*)&Vt[dst] = *(const short4v*)h4;
  }
}

// ---------------------------------------------------------------------------
// K3: GEMM  out[o][m] = sum_k W[o][k] * V[m][k]   (bf16 MFMA, fp32 acc)
// BO=128, BM=64, BK=64. grid (tm2=256, to=2), 256 thr (4 waves).
// ---------------------------------------------------------------------------
__global__ __launch_bounds__(256) void k3_gemm(const __hip_bfloat16* __restrict__ Wt,
                                               const __hip_bfloat16* __restrict__ Vt,
                                               float* __restrict__ out) {
  __shared__ __align__(16) __hip_bfloat16 sW[128 * 64];
  __shared__ __align__(16) __hip_bfloat16 sV[64 * 64];
  int tm = blockIdx.x;    // 0..255
  int to = blockIdx.y;    // 0..1
  int tid = threadIdx.x;
  int wv = tid >> 6, lane = tid & 63;
  int lo = lane & 15, hi = lane >> 4;

  f32x4 zero4 = {0.f, 0.f, 0.f, 0.f};
  f32x4 acc[2][4];
#pragma unroll
  for (int fo = 0; fo < 2; ++fo)
#pragma unroll
    for (int fm = 0; fm < 4; ++fm) acc[fo][fm] = zero4;

  const char* srcW = (const char*)(Wt + (size_t)to * NKSTEP * 8192);
  const char* srcV = (const char*)(Vt + (size_t)tm * NKSTEP * 4096);

  for (int tk = 0; tk < NKSTEP; ++tk) {
#pragma unroll
    for (int j = 0; j < 4; ++j) {
      int off = (j * 256 + tid) * 16;
      async16(srcW + (size_t)tk * 16384 + off, (char*)sW + off);
    }
#pragma unroll
    for (int j = 0; j < 2; ++j) {
      int off = (j * 256 + tid) * 16;
      async16(srcV + (size_t)tk * 8192 + off, (char*)sV + off);
    }
    __syncthreads();

    short8 a[2][2], bf[4][2];
#pragma unroll
    for (int fo = 0; fo < 2; ++fo)
#pragma unroll
      for (int kc = 0; kc < 2; ++kc)
        a[fo][kc] = *(const short8*)&sW[(wv * 32 + fo * 16 + lo) * 64 + kc * 32 + hi * 8];
#pragma unroll
    for (int fm = 0; fm < 4; ++fm)
#pragma unroll
      for (int kc = 0; kc < 2; ++kc)
        bf[fm][kc] = *(const short8*)&sV[(fm * 16 + lo) * 64 + kc * 32 + hi * 8];

#pragma unroll
    for (int fo = 0; fo < 2; ++fo)
#pragma unroll
      for (int fm = 0; fm < 4; ++fm)
#pragma unroll
        for (int kc = 0; kc < 2; ++kc)
          acc[fo][fm] = __builtin_amdgcn_mfma_f32_16x16x32_bf16(a[fo][kc], bf[fm][kc], acc[fo][fm], 0, 0, 0);
    __syncthreads();
  }

  int mbase = tm * 64;
  int b = mbase >> 12;
  int hwbase = mbase & 4095;
#pragma unroll
  for (int fo = 0; fo < 2; ++fo) {
    int o = to * 128 + wv * 32 + fo * 16 + hi * 4;
#pragma unroll
    for (int fm = 0; fm < 4; ++fm) {
      int mloc = hwbase + fm * 16 + lo;
#pragma unroll
      for (int r = 0; r < 4; ++r)
        out[((size_t)(b * 256 + o + r)) * 4096 + mloc] = acc[fo][fm][r];
    }
  }
}

// ---------------------------------------------------------------------------
extern "C" void kernel_launch(void* const* d_in, const int* in_sizes, int n_in,
                              void* d_out, int out_size, void* d_ws, size_t ws_size,
                              hipStream_t stream) {
  (void)in_sizes; (void)n_in; (void)out_size; (void)ws_size;
  const float* x     = (const float*)d_in[0];
  const float* woff  = (const float*)d_in[1];
  const float* boff  = (const float*)d_in[2];
  const float* wconv = (const float*)d_in[3];
  char* ws = (char*)d_ws;
  float* om   = (float*)(ws + OM_OFF);
  float* part = (float*)(ws + PART_OFF);   // aliases Vt region (dead before k2)
  float* xT   = (float*)(ws + XT_OFF);
  __hip_bfloat16* Wt = (__hip_bfloat16*)(ws + WT_OFF);
  __hip_bfloat16* Vt = (__hip_bfloat16*)(ws + VT_OFF);
  float* out = (float*)d_out;

  hipLaunchKernelGGL(k0_wt,       dim3(2304),     dim3(256), 0, stream, wconv, Wt);
  hipLaunchKernelGGL(k1a_offconv, dim3(64, 32),   dim3(256), 0, stream, x, woff, part);
  hipLaunchKernelGGL(k1b_reduce,  dim3(1728),     dim3(256), 0, stream, part, boff, om);
  hipLaunchKernelGGL(kt_xt,       dim3(1024),     dim3(256), 0, stream, x, xT);
  hipLaunchKernelGGL(k2_im2col,   dim3(4096),     dim3(256), 0, stream, xT, om, Vt);
  hipLaunchKernelGGL(k3_gemm,     dim3(256, 2),   dim3(256), 0, stream, Wt, Vt, out);
}

// Round 5
// 121.435 us; speedup vs baseline: 2.2054x; 2.2054x over previous
//
#include <hip/hip_runtime.h>
#include <hip/hip_bf16.h>

// Problem constants
#define XH   64
#define XW   64
#define CIN  256
#define COUT 256
#define BATCH 4
#define KK9  9
#define M_TOT 16384      // BATCH*XH*XW
#define K_TOT 2304       // KK9*CIN
#define NKSTEP 36        // K_TOT/64

typedef __attribute__((ext_vector_type(8))) short short8;
typedef __attribute__((ext_vector_type(4))) short short4v;
typedef __attribute__((ext_vector_type(4))) float f32x4;
typedef __attribute__((ext_vector_type(4))) int int4v;

// Workspace layout (bytes). WOT aliases the head of VT: Wot is consumed by
// k1_omgemm, which completes before k2 writes Vt.
#define OM_OFF   0
#define OM_BYTES (BATCH*27*4096*4)            // 1,769,472
#define XT_OFF   (OM_OFF + OM_BYTES)
#define XT_BYTES (BATCH*4096*CIN*4)           // 16,777,216
#define WT_OFF   (XT_OFF + XT_BYTES)
#define WT_BYTES (COUT*K_TOT*2)               // 1,179,648
#define VT_OFF   (WT_OFF + WT_BYTES)
#define VT_BYTES (M_TOT*K_TOT*2)              // 75,497,472
#define WOT_OFF  VT_OFF                       // 147,456 bytes, dead before k2

__device__ __forceinline__ void async16(const void* g, void* l) {
  __builtin_amdgcn_global_load_lds((const __attribute__((address_space(1))) void*)g,
                                   (__attribute__((address_space(3))) void*)l,
                                   16, 0, 0);
}

// ---------------------------------------------------------------------------
// K0: w_conv (O,C,3,3) f32  ->  Wt tiled bf16: [to(2)][tk(36)][128 o][64 k],
//     k = kk*256 + c
// ---------------------------------------------------------------------------
__global__ __launch_bounds__(256) void k0_wt(const float* __restrict__ wconv,
                                             __hip_bfloat16* __restrict__ Wt) {
  int e = blockIdx.x * 256 + threadIdx.x;      // < 256*2304 = 589824
  int t  = e >> 13;
  int r  = e & 8191;
  int ol = r >> 6, kl = r & 63;
  int to = t / 36, tk = t - to * 36;
  int o  = to * 128 + ol;
  int k  = tk * 64 + kl;
  int kk = k >> 8, c = k & 255;
  float v = wconv[(o * CIN + c) * KK9 + kk];
  Wt[e] = __float2bfloat16(v);
}

// ---------------------------------------------------------------------------
// K0b: w_off (27,C,3,3) f32 -> Wot tiled bf16: [tk(36)][32 oc][64 k]
//      (oc 27..31 zero-padded), k = kk*256 + c
// ---------------------------------------------------------------------------
__global__ __launch_bounds__(256) void k0b_wot(const float* __restrict__ woff,
                                               __hip_bfloat16* __restrict__ Wot) {
  int e = blockIdx.x * 256 + threadIdx.x;      // < 36*2048 = 73728
  int tk = e >> 11;
  int r  = e & 2047;
  int ocl = r >> 6, kl = r & 63;
  int k = tk * 64 + kl;
  int kk = k >> 8, c = k & 255;
  float v = (ocl < 27) ? woff[((size_t)(ocl * 256 + c)) * 9 + kk] : 0.f;
  Wot[e] = __float2bfloat16(v);
}

// ---------------------------------------------------------------------------
// KT: transpose x (B,C,H,W) f32 -> xT[b][hw][c] f32 (channel-contiguous)
// ---------------------------------------------------------------------------
__global__ __launch_bounds__(256) void kt_xt(const float* __restrict__ x,
                                             float* __restrict__ xT) {
  __shared__ float t[64][65];
  int blk = blockIdx.x;
  int hwg = blk & 63;
  int cg  = (blk >> 6) & 3;
  int b   = blk >> 8;
  int hw0 = hwg * 64, c0 = cg * 64;
  int l = threadIdx.x & 63, q = threadIdx.x >> 6;
  const float* xb = x + ((size_t)(b * 256 + c0) << 12) + hw0;
#pragma unroll
  for (int i = 0; i < 16; ++i) {
    int cl = q * 16 + i;
    t[cl][l] = xb[((size_t)cl << 12) + l];
  }
  __syncthreads();
  float* xTb = xT + (((size_t)b << 12) + hw0) * 256 + c0;
#pragma unroll
  for (int i = 0; i < 16; ++i) {
    int hwl = q * 16 + i;
    xTb[(size_t)hwl * 256 + l] = t[l][hwl];
  }
}

// ---------------------------------------------------------------------------
// K1: offset conv as MFMA GEMM.  om[oc][m] = sum_k Wot[oc][k] * patch[m][k],
// patch built on the fly from xT with the (ky,kx) shift of each k-tile.
// Block tile: 64 m x 32 oc. grid 256 blocks, 256 thr (4 waves; wave wv owns
// m-rows {wv*16+lo}). Each thread stages 2 m-rows x 8 k per k-step.
// ---------------------------------------------------------------------------
__global__ __launch_bounds__(256) void k1_omgemm(const float* __restrict__ xT,
                                                 const __hip_bfloat16* __restrict__ Wot,
                                                 const float* __restrict__ boff,
                                                 float* __restrict__ om) {
  __shared__ __align__(16) __hip_bfloat16 sP[64 * 64];
  __shared__ __align__(16) __hip_bfloat16 sWo[32 * 64];
  int tm = blockIdx.x;          // 0..255
  int tid = threadIdx.x;
  int wv = tid >> 6, lane = tid & 63;
  int lo = lane & 15, hi = lane >> 4;

  // staging coords: thread stages rows r0 and r0+32, 8 channels each
  int r0 = tid >> 3;            // 0..31
  int kb = (tid & 7) * 8;       // 0..56

  f32x4 zero4 = {0.f, 0.f, 0.f, 0.f};
  f32x4 acc[2] = {zero4, zero4};

  for (int tk = 0; tk < NKSTEP; ++tk) {
    async16((const char*)Wot + (size_t)tk * 4096 + tid * 16, (char*)sWo + tid * 16);

    int kk = tk >> 2, cc = tk & 3;
    int ky = kk / 3, kx = kk - ky * 3;
#pragma unroll
    for (int half = 0; half < 2; ++half) {
      int row = r0 + half * 32;
      int m_s = tm * 64 + row;
      int b_s = m_s >> 12, hw_s = m_s & 4095, h_s = hw_s >> 6, w_s = hw_s & 63;
      int yy = h_s + ky - 1, xx = w_s + kx - 1;
      bool valid = ((unsigned)yy < 64u) && ((unsigned)xx < 64u);
      short8 h8 = {0, 0, 0, 0, 0, 0, 0, 0};
      if (valid) {
        const float* src = xT + ((((size_t)b_s << 12) + yy * 64 + xx) << 8) + cc * 64 + kb;
        f32x4 u0 = *(const f32x4*)src;
        f32x4 u1 = *(const f32x4*)(src + 4);
        __hip_bfloat16 tmp[8];
#pragma unroll
        for (int j = 0; j < 4; ++j) {
          tmp[j]     = __float2bfloat16(u0[j]);
          tmp[4 + j] = __float2bfloat16(u1[j]);
        }
        h8 = *(const short8*)tmp;
      }
      *(short8*)&sP[row * 64 + kb] = h8;
    }
    __syncthreads();

    short8 bfr[2], a[2][2];
#pragma unroll
    for (int kc = 0; kc < 2; ++kc) {
      bfr[kc] = *(const short8*)&sP[(wv * 16 + lo) * 64 + kc * 32 + hi * 8];
#pragma unroll
      for (int f = 0; f < 2; ++f)
        a[f][kc] = *(const short8*)&sWo[(f * 16 + lo) * 64 + kc * 32 + hi * 8];
    }
#pragma unroll
    for (int f = 0; f < 2; ++f)
#pragma unroll
      for (int kc = 0; kc < 2; ++kc)
        acc[f] = __builtin_amdgcn_mfma_f32_16x16x32_bf16(a[f][kc], bfr[kc], acc[f], 0, 0, 0);
    __syncthreads();
  }

  // C layout: col = lane&15 -> m, row = hi*4 + r (+f*16) -> oc
  int m_o = tm * 64 + wv * 16 + lo;
  int b_o = m_o >> 12, hw_o = m_o & 4095;
#pragma unroll
  for (int f = 0; f < 2; ++f) {
#pragma unroll
    for (int r = 0; r < 4; ++r) {
      int oc = f * 16 + hi * 4 + r;
      if (oc < 27)
        om[(((size_t)(b_o * 27 + oc)) << 12) + hw_o] = acc[f][r] + boff[oc];
    }
  }
}

// ---------------------------------------------------------------------------
// K2: deformable im2col from xT -> Vt tiled bf16: [tm2(256)][tk(36)][64 m][64 k]
// One WAVE per (m); lane = 4 channels (float4); 9 kk per wave.
// ---------------------------------------------------------------------------
__global__ __launch_bounds__(256) void k2_im2col(const float* __restrict__ xT,
                                                 const float* __restrict__ om,
                                                 __hip_bfloat16* __restrict__ Vt) {
  int wv = threadIdx.x >> 6, lane = threadIdx.x & 63;
  int m = blockIdx.x * 4 + wv;
  int b = m >> 12, hw = m & 4095, h = hw >> 6, w = hw & 63;
  const float* omb = om + ((size_t)(b * 27) << 12) + hw;

  float dyv[9], dxv[9], mzv[9];
#pragma unroll
  for (int kk = 0; kk < 9; ++kk) {
    dyv[kk] = omb[(size_t)(2 * kk) << 12];
    dxv[kk] = omb[(size_t)(2 * kk + 1) << 12];
    mzv[kk] = omb[(size_t)(18 + kk) << 12];
  }

  const float* xb = xT + (((size_t)b << 12) << 8) + lane * 4;
  int tm2 = m >> 6, ml = m & 63;
  int cc = lane >> 4;
  int kl4 = (lane & 15) * 4;

#pragma unroll
  for (int kk = 0; kk < 9; ++kk) {
    int ky = kk / 3, kx = kk - ky * 3;
    float py = dyv[kk] + (float)(h - 1 + ky);
    float px = dxv[kk] + (float)(w - 1 + kx);
    float y0f = floorf(py), x0f = floorf(px);
    float wy = py - y0f, wx = px - x0f;
    int y0 = (int)y0f, x0 = (int)x0f;
    bool vy0 = (unsigned)y0 < 64u, vy1 = (unsigned)(y0 + 1) < 64u;
    bool vx0 = (unsigned)x0 < 64u, vx1 = (unsigned)(x0 + 1) < 64u;
    int cy0 = min(max(y0, 0), 63), cy1 = min(max(y0 + 1, 0), 63);
    int cx0 = min(max(x0, 0), 63), cx1 = min(max(x0 + 1, 0), 63);
    float mask = 1.f / (1.f + __expf(-mzv[kk]));
    float w00 = (vy0 && vx0) ? (1.f - wy) * (1.f - wx) * mask : 0.f;
    float w01 = (vy0 && vx1) ? (1.f - wy) * wx * mask : 0.f;
    float w10 = (vy1 && vx0) ? wy * (1.f - wx) * mask : 0.f;
    float w11 = (vy1 && vx1) ? wy * wx * mask : 0.f;

    f32x4 t00 = *(const f32x4*)(xb + (size_t)(cy0 * 64 + cx0) * 256);
    f32x4 t01 = *(const f32x4*)(xb + (size_t)(cy0 * 64 + cx1) * 256);
    f32x4 t10 = *(const f32x4*)(xb + (size_t)(cy1 * 64 + cx0) * 256);
    f32x4 t11 = *(const f32x4*)(xb + (size_t)(cy1 * 64 + cx1) * 256);

    f32x4 v;
#pragma unroll
    for (int j = 0; j < 4; ++j)
      v[j] = w00 * t00[j] + w01 * t01[j] + w10 * t10[j] + w11 * t11[j];

    __hip_bfloat16 h4[4];
#pragma unroll
    for (int j = 0; j < 4; ++j) h4[j] = __float2bfloat16(v[j]);

    int tk = kk * 4 + cc;
    size_t dst = (((size_t)(tm2 * 36 + tk)) << 12) + (size_t)ml * 64 + kl4;
    *(short4v*)&Vt[dst] = *(const short4v*)h4;
  }
}

// ---------------------------------------------------------------------------
// K3: GEMM  out[o][m] = sum_k W[o][k] * V[m][k]   (bf16 MFMA, fp32 acc)
// BO=128, BM=64, BK=64. grid (tm2=256, to=2), 256 thr (4 waves).
// ---------------------------------------------------------------------------
__global__ __launch_bounds__(256) void k3_gemm(const __hip_bfloat16* __restrict__ Wt,
                                               const __hip_bfloat16* __restrict__ Vt,
                                               float* __restrict__ out) {
  __shared__ __align__(16) __hip_bfloat16 sW[128 * 64];
  __shared__ __align__(16) __hip_bfloat16 sV[64 * 64];
  int tm = blockIdx.x;    // 0..255
  int to = blockIdx.y;    // 0..1
  int tid = threadIdx.x;
  int wv = tid >> 6, lane = tid & 63;
  int lo = lane & 15, hi = lane >> 4;

  f32x4 zero4 = {0.f, 0.f, 0.f, 0.f};
  f32x4 acc[2][4];
#pragma unroll
  for (int fo = 0; fo < 2; ++fo)
#pragma unroll
    for (int fm = 0; fm < 4; ++fm) acc[fo][fm] = zero4;

  const char* srcW = (const char*)(Wt + (size_t)to * NKSTEP * 8192);
  const char* srcV = (const char*)(Vt + (size_t)tm * NKSTEP * 4096);

  for (int tk = 0; tk < NKSTEP; ++tk) {
#pragma unroll
    for (int j = 0; j < 4; ++j) {
      int off = (j * 256 + tid) * 16;
      async16(srcW + (size_t)tk * 16384 + off, (char*)sW + off);
    }
#pragma unroll
    for (int j = 0; j < 2; ++j) {
      int off = (j * 256 + tid) * 16;
      async16(srcV + (size_t)tk * 8192 + off, (char*)sV + off);
    }
    __syncthreads();

    short8 a[2][2], bf[4][2];
#pragma unroll
    for (int fo = 0; fo < 2; ++fo)
#pragma unroll
      for (int kc = 0; kc < 2; ++kc)
        a[fo][kc] = *(const short8*)&sW[(wv * 32 + fo * 16 + lo) * 64 + kc * 32 + hi * 8];
#pragma unroll
    for (int fm = 0; fm < 4; ++fm)
#pragma unroll
      for (int kc = 0; kc < 2; ++kc)
        bf[fm][kc] = *(const short8*)&sV[(fm * 16 + lo) * 64 + kc * 32 + hi * 8];

#pragma unroll
    for (int fo = 0; fo < 2; ++fo)
#pragma unroll
      for (int fm = 0; fm < 4; ++fm)
#pragma unroll
        for (int kc = 0; kc < 2; ++kc)
          acc[fo][fm] = __builtin_amdgcn_mfma_f32_16x16x32_bf16(a[fo][kc], bf[fm][kc], acc[fo][fm], 0, 0, 0);
    __syncthreads();
  }

  int mbase = tm * 64;
  int b = mbase >> 12;
  int hwbase = mbase & 4095;
#pragma unroll
  for (int fo = 0; fo < 2; ++fo) {
    int o = to * 128 + wv * 32 + fo * 16 + hi * 4;
#pragma unroll
    for (int fm = 0; fm < 4; ++fm) {
      int mloc = hwbase + fm * 16 + lo;
#pragma unroll
      for (int r = 0; r < 4; ++r)
        out[((size_t)(b * 256 + o + r)) * 4096 + mloc] = acc[fo][fm][r];
    }
  }
}

// ---------------------------------------------------------------------------
extern "C" void kernel_launch(void* const* d_in, const int* in_sizes, int n_in,
                              void* d_out, int out_size, void* d_ws, size_t ws_size,
                              hipStream_t stream) {
  (void)in_sizes; (void)n_in; (void)out_size; (void)ws_size;
  const float* x     = (const float*)d_in[0];
  const float* woff  = (const float*)d_in[1];
  const float* boff  = (const float*)d_in[2];
  const float* wconv = (const float*)d_in[3];
  char* ws = (char*)d_ws;
  float* om   = (float*)(ws + OM_OFF);
  float* xT   = (float*)(ws + XT_OFF);
  __hip_bfloat16* Wt  = (__hip_bfloat16*)(ws + WT_OFF);
  __hip_bfloat16* Vt  = (__hip_bfloat16*)(ws + VT_OFF);
  __hip_bfloat16* Wot = (__hip_bfloat16*)(ws + WOT_OFF);   // aliases head of Vt (dead before k2)
  float* out = (float*)d_out;

  hipLaunchKernelGGL(k0_wt,     dim3(2304),   dim3(256), 0, stream, wconv, Wt);
  hipLaunchKernelGGL(k0b_wot,   dim3(288),    dim3(256), 0, stream, woff, Wot);
  hipLaunchKernelGGL(kt_xt,     dim3(1024),   dim3(256), 0, stream, x, xT);
  hipLaunchKernelGGL(k1_omgemm, dim3(256),    dim3(256), 0, stream, xT, Wot, boff, om);
  hipLaunchKernelGGL(k2_im2col, dim3(4096),   dim3(256), 0, stream, xT, om, Vt);
  hipLaunchKernelGGL(k3_gemm,   dim3(256, 2), dim3(256), 0, stream, Wt, Vt, out);
}